// Round 1
// baseline (7430.409 us; speedup 1.0000x reference)
//
#include <hip/hip_runtime.h>

// Sizes
#define B_SZ 256
#define T_SZ 1024
#define H_SZ 512
#define NG   16   // batch groups
#define NS   16   // h slices
#define BM   16   // batch rows per group
#define HS   32   // h elems per slice

typedef short bf16x8 __attribute__((ext_vector_type(8)));
typedef float f32x4  __attribute__((ext_vector_type(4)));

__device__ __forceinline__ unsigned f2bf(float f) {
  unsigned u = __builtin_bit_cast(unsigned, f);
  return (u + 0x7fffu + ((u >> 16) & 1u)) >> 16;   // RTNE fp32->bf16
}

// ---------------- Phase 1: GRU over time, weight-stationary N-split ----------
// grid = 256 wgs: g = blockIdx.x & 15 (batch group), slice = blockIdx.x >> 4.
// Each wg owns h-slice [slice*32, slice*32+32) for batch rows [g*16, g*16+16).
// W_hh slice lives in VGPRs as MFMA B-frags. h exchanged per step through
// global hbuf (bf16 pairs) with per-slice monotonic flags (agent scope).
__global__ void __launch_bounds__(512) gru_phase1(
    const float* __restrict__ V,
    const float* __restrict__ W_ih,
    const float* __restrict__ W_hh,
    const float* __restrict__ b_ih,
    const float* __restrict__ b_hh,
    const float* __restrict__ Wr,
    float* __restrict__ res_all,      // [T][B][2] fp32, pre-zeroed
    unsigned* __restrict__ hbuf,      // [2][256][256] dwords (bf16 pairs)
    unsigned* __restrict__ flags)     // [(g*16+slice)*16], monotonic step count
{
  const int tid  = threadIdx.x;
  const int wid  = tid >> 6;
  const int lane = tid & 63;
  const int g     = blockIdx.x & 15;
  const int slice = blockIdx.x >> 4;

  __shared__ unsigned h_stage[4096];   // 16KB swizzled bf16 [16][512]
  __shared__ float    gh_lds[16 * 100];
  __shared__ float    h_own[512];      // fp32 h state for own slice

  // ---- pointwise-role constants (thread = row*32 + idx) ----
  const int prow = tid >> 5;
  const int pidx = tid & 31;
  const int hcol = slice * HS + pidx;        // global h column owned
  const int bglob = g * BM + prow;           // global batch row
  const float wir0 = W_ih[hcol * 2 + 0],          wir1 = W_ih[hcol * 2 + 1];
  const float wiz0 = W_ih[(512 + hcol) * 2 + 0],  wiz1 = W_ih[(512 + hcol) * 2 + 1];
  const float win0 = W_ih[(1024 + hcol) * 2 + 0], win1 = W_ih[(1024 + hcol) * 2 + 1];
  const float bsr = b_ih[hcol] + b_hh[hcol];
  const float bsz = b_ih[512 + hcol] + b_hh[512 + hcol];
  const float bin = b_ih[1024 + hcol];
  const float bhn = b_hh[1024 + hcol];
  const float wr0 = Wr[hcol], wr1 = Wr[512 + hcol];

  // ---- B-frag preload (waves 0..5: wave w owns gate-outs [w*16, w*16+16)) ----
  bf16x8 wf[16];
  if (wid < 6) {
    const int gate = wid >> 1;                       // 0:r 1:z 2:n
    const int grow = gate * 512 + slice * HS + (wid & 1) * 16 + (lane & 15);
    const int koff = (lane >> 4) * 8;
    #pragma unroll
    for (int kt = 0; kt < 16; kt++) {
      const float* src = W_hh + grow * 512 + kt * 32 + koff;
      bf16x8 w;
      #pragma unroll
      for (int i = 0; i < 8; i++) w[i] = (short)f2bf(src[i]);
      wf[kt] = w;
    }
  }

  for (int i = tid; i < 1600; i += 512) gh_lds[i] = 0.f;
  h_own[tid] = 0.f;
  __syncthreads();

  const int flag_self = (g * 16 + slice) * 16;

  for (int s = 0; s < T_SZ; s++) {
    // V for this step (issued early; latency hides under spin/stage/MFMA)
    const float2 vv = *reinterpret_cast<const float2*>(&V[(bglob * T_SZ + s) * 2]);

    if (s > 0) {
      // ---- wait for all 16 slices of h(s-1) ----
      if (tid < 16) {
        int guard = 0;
        while (__hip_atomic_load(&flags[(g * 16 + tid) * 16], __ATOMIC_ACQUIRE,
                                 __HIP_MEMORY_SCOPE_AGENT) < (unsigned)s) {
          __builtin_amdgcn_s_sleep(1);
          if (++guard > (1 << 24)) break;   // hang insurance -> fast wrong answer
        }
      }
      __syncthreads();
      // ---- stage h(s-1) into LDS (XOR-swizzled 16B units) ----
      {
        const unsigned pbase = ((unsigned)(s - 1) & 1u) * 65536u + (unsigned)g * 4096u;
        unsigned vals[8];
        #pragma unroll
        for (int q = 0; q < 8; q++)
          vals[q] = __hip_atomic_load(&hbuf[pbase + q * 512 + tid], __ATOMIC_RELAXED,
                                      __HIP_MEMORY_SCOPE_AGENT);
        #pragma unroll
        for (int q = 0; q < 8; q++) {
          unsigned d = q * 512 + tid;
          unsigned row = d >> 8, k16 = (d >> 2) & 63, off = d & 3;
          h_stage[row * 256 + ((k16 ^ (row & 7)) << 2) + off] = vals[q];
        }
      }
      __syncthreads();
      // ---- gh slice = h(s-1) @ Whh_slice^T via MFMA ----
      if (wid < 6) {
        f32x4 acc = {0.f, 0.f, 0.f, 0.f};
        const unsigned lrow = lane & 15;     // A row (batch row)
        const unsigned hi   = lane >> 4;     // k quarter
        const unsigned rb = lrow * 256, sw = lrow & 7;
        #pragma unroll
        for (int kt = 0; kt < 16; kt++) {
          unsigned k16 = kt * 4 + hi;
          bf16x8 a = *reinterpret_cast<const bf16x8*>(&h_stage[rb + ((k16 ^ sw) << 2)]);
          acc = __builtin_amdgcn_mfma_f32_16x16x32_bf16(a, wf[kt], acc, 0, 0, 0);
        }
        #pragma unroll
        for (int j = 0; j < 4; j++)
          gh_lds[(hi * 4 + j) * 100 + wid * 16 + lrow] = acc[j];
      }
      __syncthreads();
    }

    // ---- pointwise GRU update (all 512 threads; s==0 reads zeroed gh) ----
    const float ghr = gh_lds[prow * 100 + pidx];
    const float ghz = gh_lds[prow * 100 + 32 + pidx];
    const float ghn = gh_lds[prow * 100 + 64 + pidx];
    const float hp = h_own[tid];
    float pr = ghr + bsr + wir0 * vv.x + wir1 * vv.y;
    float pz = ghz + bsz + wiz0 * vv.x + wiz1 * vv.y;
    float rg = 1.f / (1.f + __expf(-pr));
    float zg = 1.f / (1.f + __expf(-pz));
    float pn = win0 * vv.x + win1 * vv.y + bin + rg * (ghn + bhn);
    pn = fminf(fmaxf(pn, -30.f), 30.f);
    float e2 = __expf(2.f * pn);
    float ng = (e2 - 1.f) / (e2 + 1.f);
    float hn = (1.f - zg) * ng + zg * hp;
    h_own[tid] = hn;

    // ---- publish h(s) (bf16 pairs, device-coherent) ----
    float ho = __shfl_xor(hn, 1);
    if (!(pidx & 1)) {
      unsigned w = f2bf(hn) | (f2bf(ho) << 16);
      __hip_atomic_store(&hbuf[((unsigned)s & 1u) * 65536u + (unsigned)bglob * 256u +
                               (unsigned)slice * 16u + (unsigned)(pidx >> 1)],
                         w, __ATOMIC_RELAXED, __HIP_MEMORY_SCOPE_AGENT);
    }

    // ---- res partial: Wr[:, slice] . h_new(slice)  (fp32, off critical path) ----
    float p0 = hn * wr0, p1 = hn * wr1;
    #pragma unroll
    for (int m = 1; m < 32; m <<= 1) {
      p0 += __shfl_xor(p0, m);
      p1 += __shfl_xor(p1, m);
    }
    if (pidx == 0) {
      atomicAdd(&res_all[(s * B_SZ + bglob) * 2 + 0], p0);
      atomicAdd(&res_all[(s * B_SZ + bglob) * 2 + 1], p1);
    }

    __syncthreads();                      // drains all waves' vmcnt before flag
    if (tid == 0)
      __hip_atomic_store(&flags[flag_self], (unsigned)(s + 1), __ATOMIC_RELEASE,
                         __HIP_MEMORY_SCOPE_AGENT);
  }
}

// ---------------- Phase 2: correction scan (one wave per batch row) ----------
__global__ void __launch_bounds__(256) corr_phase2(
    const float* __restrict__ X0,
    const float* __restrict__ V,
    const float* __restrict__ Wa1,
    const float* __restrict__ ba1,
    const float* __restrict__ Wa2,
    const float* __restrict__ ba2,
    const float* __restrict__ br,
    const float* __restrict__ res_all,
    float* __restrict__ out)
{
  const int tid = threadIdx.x;
  const int wv = tid >> 6;
  const int lane = tid & 63;
  const int b = blockIdx.x * 4 + wv;

  // lane owns hid units h = lane*4 + q
  float w1[4][4], bb1[4], w20[4], w21[4];
  #pragma unroll
  for (int q = 0; q < 4; q++) {
    const int h = lane * 4 + q;
    #pragma unroll
    for (int c = 0; c < 4; c++) w1[q][c] = Wa1[h * 4 + c];
    bb1[q] = ba1[h];
    w20[q] = Wa2[h];
    w21[q] = Wa2[256 + h];
  }
  const float c20 = ba2[0], c21 = ba2[1];
  const float br0 = br[0], br1 = br[1];
  float x0 = X0[b * 2], x1 = X0[b * 2 + 1];

  for (int c = 0; c < 16; c++) {
    const int tl = c * 64 + lane;
    const float2 vvl = *reinterpret_cast<const float2*>(&V[(b * 1024 + tl) * 2]);
    const float2 rrl = *reinterpret_cast<const float2*>(&res_all[(tl * 256 + b) * 2]);
    float sx = 0.f, sy = 0.f;
    for (int k = 0; k < 64; k++) {
      const float v0 = __shfl(vvl.x, k);
      const float v1 = __shfl(vvl.y, k);
      const float r0 = __shfl(rrl.x, k) + br0;
      const float r1 = __shfl(rrl.y, k) + br1;
      float l0 = 0.f, l1 = 0.f;
      #pragma unroll
      for (int q = 0; q < 4; q++) {
        float hq = w1[q][0] * x0 + w1[q][1] * x1 + w1[q][2] * v0 + w1[q][3] * v1 + bb1[q];
        hq = fmaxf(hq, 0.f);
        l0 += w20[q] * hq;
        l1 += w21[q] * hq;
      }
      #pragma unroll
      for (int m = 1; m < 64; m <<= 1) {
        l0 += __shfl_xor(l0, m);
        l1 += __shfl_xor(l1, m);
      }
      l0 += c20; l1 += c21;
      const float mx = fmaxf(l0, l1);
      const float e0 = __expf(l0 - mx), e1 = __expf(l1 - mx);
      const float inv = 1.f / (e0 + e1);
      x0 += v0 + (e0 * inv) * r0;
      x1 += v1 + (e1 * inv) * r1;
      if (k == lane) { sx = x0; sy = x1; }
    }
    float2 o; o.x = sx; o.y = sy;
    *reinterpret_cast<float2*>(&out[(b * 1024 + c * 64 + lane) * 2]) = o;
  }
}

extern "C" void kernel_launch(void* const* d_in, const int* in_sizes, int n_in,
                              void* d_out, int out_size, void* d_ws, size_t ws_size,
                              hipStream_t stream) {
  const float* X0   = (const float*)d_in[0];
  const float* V    = (const float*)d_in[1];
  const float* W_ih = (const float*)d_in[2];
  const float* W_hh = (const float*)d_in[3];
  const float* b_ih = (const float*)d_in[4];
  const float* b_hh = (const float*)d_in[5];
  const float* Wa1  = (const float*)d_in[6];
  const float* ba1  = (const float*)d_in[7];
  const float* Wa2  = (const float*)d_in[8];
  const float* ba2  = (const float*)d_in[9];
  const float* Wr   = (const float*)d_in[10];
  const float* br   = (const float*)d_in[11];
  float* out = (float*)d_out;

  char* ws = (char*)d_ws;
  float*    res_all = (float*)ws;                                   // 2 MB
  unsigned* hbuf    = (unsigned*)(ws + 2 * 1024 * 1024);            // 512 KB
  unsigned* flags   = (unsigned*)(ws + 2 * 1024 * 1024 + 512 * 1024); // 16 KB
  const size_t total = 2 * 1024 * 1024 + 512 * 1024 + 16 * 1024;
  hipMemsetAsync(d_ws, 0, total, stream);

  hipLaunchKernelGGL(gru_phase1, dim3(256), dim3(512), 0, stream,
                     V, W_ih, W_hh, b_ih, b_hh, Wr, res_all, hbuf, flags);
  hipLaunchKernelGGL(corr_phase2, dim3(64), dim3(256), 0, stream,
                     X0, V, Wa1, ba1, Wa2, ba2, br, res_all, out);
}